// Round 1
// baseline (566.563 us; speedup 1.0000x reference)
//
#include <hip/hip_runtime.h>
#include <hip/hip_bf16.h>

using bf16 = __hip_bfloat16;
typedef __attribute__((ext_vector_type(4))) float f32x4;
typedef __attribute__((ext_vector_type(8))) short bf16x8;   // 8 bf16 = 4 VGPRs (MFMA A/B frag)

constexpr int Ntok   = 4096;
constexpr int Cdim   = 768;
constexpr int Hn     = 6;
constexpr int HD     = 128;
constexpr int QKcols = 1536;   // 2*Cdim

#define AS1 __attribute__((address_space(1)))
#define AS3 __attribute__((address_space(3)))

__device__ inline void gload_lds16(const bf16* g, bf16* l) {
    __builtin_amdgcn_global_load_lds((const AS1 void*)g, (AS3 void*)l, 16, 0, 0);
}

__device__ inline int4 cvt8_f32_to_bf16(const float* p) {
    const float4 a0 = *reinterpret_cast<const float4*>(p);
    const float4 a1 = *reinterpret_cast<const float4*>(p + 4);
    union { int4 i; bf16 h[8]; } u;
    u.h[0] = __float2bfloat16(a0.x); u.h[1] = __float2bfloat16(a0.y);
    u.h[2] = __float2bfloat16(a0.z); u.h[3] = __float2bfloat16(a0.w);
    u.h[4] = __float2bfloat16(a1.x); u.h[5] = __float2bfloat16(a1.y);
    u.h[6] = __float2bfloat16(a1.z); u.h[7] = __float2bfloat16(a1.w);
    return u.i;
}

// ---------------------------------------------------------------------------
// fp32 -> bf16 bulk convert. 8 elems/thread.
// ---------------------------------------------------------------------------
__global__ __launch_bounds__(256) void cvt_kernel(const float* __restrict__ in,
                                                  bf16* __restrict__ out) {
    const size_t i = ((size_t)blockIdx.x * 256 + threadIdx.x) * 8;
    *reinterpret_cast<int4*>(out + i) = cvt8_f32_to_bf16(in + i);
}

// ---------------------------------------------------------------------------
// Transpose + cast: W[K][N] fp32 -> Wt[N][K] bf16
// ---------------------------------------------------------------------------
__global__ void transpose_kernel(const float* __restrict__ W, bf16* __restrict__ Wt,
                                 int K, int N) {
    __shared__ bf16 tile[32][33];
    const int n0 = blockIdx.x * 32, k0 = blockIdx.y * 32;
    const int tx = threadIdx.x, ty = threadIdx.y;      // blockDim (32,8)
    for (int i = 0; i < 32; i += 8)
        tile[ty + i][tx] = __float2bfloat16(W[(size_t)(k0 + ty + i) * N + n0 + tx]);
    __syncthreads();
    for (int i = 0; i < 32; i += 8)
        Wt[(size_t)(n0 + ty + i) * K + k0 + tx] = tile[tx][ty + i];
}

// ---------------------------------------------------------------------------
// GEMM: C[M][N] = A[M][K] @ Bt[N][K]^T (+bias). bf16 in, fp32 accum.
// m97 structure: 128x128 tile, BK=32, global_load_lds(16B) staging.
// bt_bstride: per-4096-row-batch stride added to Bt (0 = shared B).
// ---------------------------------------------------------------------------
template <bool C_F32, bool BIAS>
__global__ __launch_bounds__(256) void gemm_bt(const bf16* __restrict__ A,
                                               const bf16* __restrict__ Bt,
                                               const float* __restrict__ bias,
                                               void* __restrict__ Cv,
                                               int M, int N, int K, int bt_bstride) {
    __shared__ bf16 As[128 * 32];
    __shared__ bf16 Bs[128 * 32];

    const int m0   = blockIdx.y * 128, n0 = blockIdx.x * 128;
    Bt += (size_t)(m0 >> 12) * bt_bstride;           // per-batch B (4096 rows/batch)
    const int tid  = threadIdx.x;
    const int wave = tid >> 6, lane = tid & 63;
    const int wq   = wave >> 1, wr = wave & 1;
    const int lm   = lane & 15, quad = lane >> 4;

    const int srow = tid >> 2, scol = (tid & 3) * 8;
    const bf16* Ag = A  + (size_t)(m0 + srow) * K + scol;
    const bf16* Bg = Bt + (size_t)(n0 + srow) * K + scol;
    bf16* Al0 = &As[srow * 32 + scol];
    bf16* Al1 = &As[(64 + srow) * 32 + scol];
    bf16* Bl0 = &Bs[srow * 32 + scol];
    bf16* Bl1 = &Bs[(64 + srow) * 32 + scol];

    f32x4 acc[4][4] = {};

    for (int k0 = 0; k0 < K; k0 += 32) {
        __syncthreads();
        gload_lds16(Ag + k0,                  Al0);
        gload_lds16(Ag + (size_t)64 * K + k0, Al1);
        gload_lds16(Bg + k0,                  Bl0);
        gload_lds16(Bg + (size_t)64 * K + k0, Bl1);
        __syncthreads();

        bf16x8 af[4], bfr[4];
#pragma unroll
        for (int t = 0; t < 4; t++) {
            af[t]  = *reinterpret_cast<const bf16x8*>(&As[(wq * 64 + t * 16 + lm) * 32 + quad * 8]);
            bfr[t] = *reinterpret_cast<const bf16x8*>(&Bs[(wr * 64 + t * 16 + lm) * 32 + quad * 8]);
        }
#pragma unroll
        for (int mt = 0; mt < 4; mt++)
#pragma unroll
            for (int nt = 0; nt < 4; nt++)
                acc[mt][nt] = __builtin_amdgcn_mfma_f32_16x16x32_bf16(af[mt], bfr[nt], acc[mt][nt], 0, 0, 0);
    }

    const int cm = m0 + wq * 64, cn = n0 + wr * 64;
#pragma unroll
    for (int mt = 0; mt < 4; mt++) {
#pragma unroll
        for (int nt = 0; nt < 4; nt++) {
            const int col = cn + nt * 16 + lm;
            const float bv = BIAS ? bias[col] : 0.0f;
#pragma unroll
            for (int r = 0; r < 4; r++) {
                const int row = cm + mt * 16 + quad * 4 + r;
                if constexpr (C_F32)
                    ((float*)Cv)[(size_t)row * N + col] = acc[mt][nt][r] + bv;
                else
                    ((bf16*)Cv)[(size_t)row * N + col] = __float2bfloat16(acc[mt][nt][r] + bv);
            }
        }
    }
}

// ---------------------------------------------------------------------------
// Gram: G[b*768+c][d] = sum_n xb[b,n,c]*xb[b,n,d]  (bf16 out, fp32 accum)
// Upper-triangular tile enumeration (21 tiles) + mirror write. grid (21, 8).
// ---------------------------------------------------------------------------
__global__ __launch_bounds__(256) void gram_x_kernel(const bf16* __restrict__ xb,
                                                     bf16* __restrict__ G) {
    constexpr int BKn = 64;
    constexpr int LDT = BKn + 8;                // 72: 2-way bank aliasing only (free)
    __shared__ bf16 Qt[HD * LDT];
    __shared__ bf16 Kt[HD * LDT];

    // tile t -> (ci, di), ci <= di, 6x6 upper incl diag
    int ci = 0, rem = blockIdx.x, rowlen = 6;
    while (rem >= rowlen) { rem -= rowlen; rowlen--; ci++; }
    const int di = ci + rem;
    const int b = blockIdx.y;
    const int c0 = ci * 128, d0 = di * 128;

    const int tid = threadIdx.x, wave = tid >> 6, lane = tid & 63;
    const int lm = lane & 15, quad = lane >> 4;
    const size_t base = (size_t)b * Ntok * Cdim;

    f32x4 acc[2][8] = {};

    for (int n0 = 0; n0 < Ntok; n0 += BKn) {
        __syncthreads();
#pragma unroll
        for (int r = 0; r < 4; r++) {
            const int chunk = tid + 256 * r;     // 0..1023 = 64 nl x 16 j-groups
            const int nl = chunk & 63;
            const int j0 = (chunk >> 6) * 8;
            bf16 vq[8], vk[8];
            *reinterpret_cast<int4*>(vq) = *reinterpret_cast<const int4*>(xb + base + (size_t)(n0 + nl) * Cdim + c0 + j0);
            *reinterpret_cast<int4*>(vk) = *reinterpret_cast<const int4*>(xb + base + (size_t)(n0 + nl) * Cdim + d0 + j0);
#pragma unroll
            for (int u = 0; u < 8; u++) {
                Qt[(j0 + u) * LDT + nl] = vq[u];
                Kt[(j0 + u) * LDT + nl] = vk[u];
            }
        }
        __syncthreads();
#pragma unroll
        for (int ks = 0; ks < 2; ks++) {
            bf16x8 aq[2], bk[8];
#pragma unroll
            for (int mt = 0; mt < 2; mt++)
                aq[mt] = *reinterpret_cast<const bf16x8*>(&Qt[(wave * 32 + mt * 16 + lm) * LDT + ks * 32 + quad * 8]);
#pragma unroll
            for (int dt = 0; dt < 8; dt++)
                bk[dt] = *reinterpret_cast<const bf16x8*>(&Kt[(dt * 16 + lm) * LDT + ks * 32 + quad * 8]);
#pragma unroll
            for (int mt = 0; mt < 2; mt++)
#pragma unroll
                for (int dt = 0; dt < 8; dt++)
                    acc[mt][dt] = __builtin_amdgcn_mfma_f32_16x16x32_bf16(aq[mt], bk[dt], acc[mt][dt], 0, 0, 0);
        }
    }

    bf16* Gb = G + (size_t)b * Cdim * Cdim;
#pragma unroll
    for (int mt = 0; mt < 2; mt++)
#pragma unroll
        for (int dt = 0; dt < 8; dt++)
#pragma unroll
            for (int r = 0; r < 4; r++) {
                const int c = wave * 32 + mt * 16 + quad * 4 + r;
                const int d = dt * 16 + lm;
                const bf16 v = __float2bfloat16(acc[mt][dt][r]);
                Gb[(size_t)(c0 + c) * Cdim + d0 + d] = v;
                if (ci != di) Gb[(size_t)(d0 + d) * Cdim + c0 + c] = v;
            }
}

// ---------------------------------------------------------------------------
// Per-(b,h) head kernel. grid 48, block 256. All of:
//   invq[c] = 1/max(sqrt(sum_r Wq[r,c]*GWq[r,c]), eps)   (and invk)
//   L[c,d]  = sum_r Wq[r,c]*GWk[r,d]  * invq*invk*temp
//   attn    = softmax_d(L)            (in-register)
//   WeffT[b][j][h*128+d] = sum_c attn[c,d]*Wproj[h*128+c][j]
// ---------------------------------------------------------------------------
__global__ __launch_bounds__(256) void head_kernel(const bf16* __restrict__ GW,
                                                   const bf16* __restrict__ Wtq,   // [1536][768]
                                                   const bf16* __restrict__ Wtp,   // [768][768]
                                                   const float* __restrict__ temp,
                                                   bf16* __restrict__ WeffT) {     // [8][768][768]
    constexpr int LDT = 72;                     // Kt stage [128 d][72]
    constexpr int LDP = 136;                    // attnT [128 d][136 c]  (272B rows: 16B aligned, 2-way banks)
    __shared__ bf16 Kt[HD * LDT];               // 18.4 KB
    __shared__ bf16 At[HD * LDP];               // 34.8 KB
    __shared__ float invq[HD], invk[HD];

    const int bh = blockIdx.x, b = bh / Hn, h = bh % Hn;
    const int tid = threadIdx.x, wave = tid >> 6, lane = tid & 63;
    const int lm = lane & 15, quad = lane >> 4;
    const int qoff = h * HD, koff = Cdim + h * HD;
    const float th = temp[h];

    // ---- phase 1: inverse norms (diag of W^T G W via GW columns) ----
    {
        const int cl = tid & 127;
        const bool isk = tid >= 128;
        const int colg = (isk ? koff : qoff) + cl;
        const bf16* wt = Wtq + (size_t)colg * Cdim;                   // contiguous over r
        const bf16* gw = GW + (size_t)b * Cdim * QKcols + colg;       // stride QKcols
        float s = 0.0f;
        for (int r = 0; r < Cdim; r += 8) {
            bf16 wv[8];
            *reinterpret_cast<int4*>(wv) = *reinterpret_cast<const int4*>(wt + r);
#pragma unroll
            for (int u = 0; u < 8; u++)
                s += (float)wv[u] * (float)gw[(size_t)(r + u) * QKcols];
        }
        (isk ? invk : invq)[cl] = 1.0f / fmaxf(sqrtf(fmaxf(s, 0.0f)), 1e-12f);
    }

    // ---- phase 2: logits L[c,d] = sum_r Wtq[qoff+c][r] * GW[b*768+r][koff+d] ----
    f32x4 acc[2][8] = {};
    const bf16* GWk = GW + (size_t)b * Cdim * QKcols + koff;
    for (int r0 = 0; r0 < Cdim; r0 += 64) {
        __syncthreads();
#pragma unroll
        for (int rr = 0; rr < 4; rr++) {
            const int chunk = tid + 256 * rr;
            const int rl = chunk & 63;
            const int j0 = (chunk >> 6) * 8;
            bf16 vk[8];
            *reinterpret_cast<int4*>(vk) = *reinterpret_cast<const int4*>(GWk + (size_t)(r0 + rl) * QKcols + j0);
#pragma unroll
            for (int u = 0; u < 8; u++)
                Kt[(j0 + u) * LDT + rl] = vk[u];
        }
        __syncthreads();
#pragma unroll
        for (int ks = 0; ks < 2; ks++) {
            bf16x8 aq[2], bk[8];
#pragma unroll
            for (int mt = 0; mt < 2; mt++)
                aq[mt] = *reinterpret_cast<const bf16x8*>(Wtq + (size_t)(qoff + wave * 32 + mt * 16 + lm) * Cdim + r0 + ks * 32 + quad * 8);
#pragma unroll
            for (int dt = 0; dt < 8; dt++)
                bk[dt] = *reinterpret_cast<const bf16x8*>(&Kt[(dt * 16 + lm) * LDT + ks * 32 + quad * 8]);
#pragma unroll
            for (int mt = 0; mt < 2; mt++)
#pragma unroll
                for (int dt = 0; dt < 8; dt++)
                    acc[mt][dt] = __builtin_amdgcn_mfma_f32_16x16x32_bf16(aq[mt], bk[dt], acc[mt][dt], 0, 0, 0);
        }
    }

    // ---- phase 3: scale + softmax over d, in-register; write attn^T to LDS ----
    __syncthreads();
    float ikv[8];
#pragma unroll
    for (int dt = 0; dt < 8; dt++) ikv[dt] = invk[dt * 16 + lm] * th;
#pragma unroll
    for (int mt = 0; mt < 2; mt++) {
#pragma unroll
        for (int r = 0; r < 4; r++) {
            const int c = wave * 32 + mt * 16 + quad * 4 + r;
            const float iq = invq[c];
            float v[8], m = -1e30f;
#pragma unroll
            for (int dt = 0; dt < 8; dt++) { v[dt] = acc[mt][dt][r] * iq * ikv[dt]; m = fmaxf(m, v[dt]); }
            m = fmaxf(m, __shfl_xor(m, 1, 64));
            m = fmaxf(m, __shfl_xor(m, 2, 64));
            m = fmaxf(m, __shfl_xor(m, 4, 64));
            m = fmaxf(m, __shfl_xor(m, 8, 64));
            float sum = 0.0f;
#pragma unroll
            for (int dt = 0; dt < 8; dt++) { v[dt] = __expf(v[dt] - m); sum += v[dt]; }
            sum += __shfl_xor(sum, 1, 64);
            sum += __shfl_xor(sum, 2, 64);
            sum += __shfl_xor(sum, 4, 64);
            sum += __shfl_xor(sum, 8, 64);
            const float inv = 1.0f / sum;
#pragma unroll
            for (int dt = 0; dt < 8; dt++)
                At[(dt * 16 + lm) * LDP + c] = __float2bfloat16(v[dt] * inv);
        }
    }
    __syncthreads();

    // ---- phase 4: WeffT[j][h*128+d] = sum_c Wtp[j][h*128+c] * At[d][c] ----
    bf16* Wo = WeffT + (size_t)b * Cdim * Cdim + h * HD;
    for (int jo = 0; jo < Cdim; jo += 256) {
        const int jb = jo + wave * 64;
        f32x4 a2[4][8] = {};
#pragma unroll
        for (int ks = 0; ks < 4; ks++) {
            bf16x8 aw[4], bp[8];
#pragma unroll
            for (int mt = 0; mt < 4; mt++)
                aw[mt] = *reinterpret_cast<const bf16x8*>(Wtp + (size_t)(jb + mt * 16 + lm) * Cdim + h * HD + ks * 32 + quad * 8);
#pragma unroll
            for (int dt = 0; dt < 8; dt++)
                bp[dt] = *reinterpret_cast<const bf16x8*>(&At[(dt * 16 + lm) * LDP + ks * 32 + quad * 8]);
#pragma unroll
            for (int mt = 0; mt < 4; mt++)
#pragma unroll
                for (int dt = 0; dt < 8; dt++)
                    a2[mt][dt] = __builtin_amdgcn_mfma_f32_16x16x32_bf16(aw[mt], bp[dt], a2[mt][dt], 0, 0, 0);
        }
#pragma unroll
        for (int mt = 0; mt < 4; mt++)
#pragma unroll
            for (int dt = 0; dt < 8; dt++)
#pragma unroll
                for (int r = 0; r < 4; r++)
                    Wo[(size_t)(jb + mt * 16 + quad * 4 + r) * Cdim + dt * 16 + lm] =
                        __float2bfloat16(a2[mt][dt][r]);
    }
}

// ---------------------------------------------------------------------------
extern "C" void kernel_launch(void* const* d_in, const int* in_sizes, int n_in,
                              void* d_out, int out_size, void* d_ws, size_t ws_size,
                              hipStream_t stream) {
    const float* x     = (const float*)d_in[0];
    const float* y     = (const float*)d_in[1];
    const float* Wqkv  = (const float*)d_in[2];
    const float* temp  = (const float*)d_in[3];
    const float* Wproj = (const float*)d_in[4];
    const float* bproj = (const float*)d_in[5];
    float* out = (float*)d_out;

    char* ws = (char*)d_ws;
    size_t o = 0;
    bf16* xb      = (bf16*)(ws + o); o += (size_t)32768 * 768 * 2;    // 50.3 MB
    bf16* yb      = (bf16*)(ws + o); o += (size_t)32768 * 768 * 2;    // 50.3 MB
    bf16* G       = (bf16*)(ws + o); o += (size_t)8 * 768 * 768 * 2;  //  9.4 MB
    bf16* GW      = (bf16*)(ws + o); o += (size_t)8 * 768 * 1536 * 2; // 18.9 MB
    bf16* WeffT   = (bf16*)(ws + o); o += (size_t)8 * 768 * 768 * 2;  //  9.4 MB
    bf16* Wt_qkv  = (bf16*)(ws + o); o += (size_t)1536 * 768 * 2;
    bf16* Wt_proj = (bf16*)(ws + o); o += (size_t)768 * 768 * 2;

    dim3 tb(32, 8);
    transpose_kernel<<<dim3(1536 / 32, 768 / 32), tb, 0, stream>>>(Wqkv, Wt_qkv, 768, 1536);
    transpose_kernel<<<dim3(768 / 32, 768 / 32), tb, 0, stream>>>(Wproj, Wt_proj, 768, 768);

    cvt_kernel<<<12288, 256, 0, stream>>>(x, xb);
    cvt_kernel<<<12288, 256, 0, stream>>>(y, yb);

    // G_b = x_b^T x_b  (8 batches, 768x768, symmetric: 21 tiles each)
    gram_x_kernel<<<dim3(21, 8), 256, 0, stream>>>(xb, G);

    // GW = G @ W_qkv   [6144 x 1536, K=768]
    gemm_bt<false, false><<<dim3(1536 / 128, 6144 / 128), 256, 0, stream>>>(
        G, Wt_qkv, nullptr, GW, 6144, 1536, 768, 0);

    // norms + logits + softmax + Weff fold (48 blocks: one per (b,h))
    head_kernel<<<48, 256, 0, stream>>>(GW, Wt_qkv, Wt_proj, temp, WeffT);

    // out = y_b @ Weff_b + b_proj   [32768 x 768, K=768], per-batch B
    gemm_bt<true, true><<<dim3(768 / 128, 32768 / 128), 256, 0, stream>>>(
        yb, WeffT, bproj, out, 32768, 768, 768, 768 * 768);
}

// Round 2
// 489.433 us; speedup vs baseline: 1.1576x; 1.1576x over previous
//
#include <hip/hip_runtime.h>
#include <hip/hip_bf16.h>

using bf16 = __hip_bfloat16;
typedef __attribute__((ext_vector_type(4))) float f32x4;
typedef __attribute__((ext_vector_type(8))) short bf16x8;   // 8 bf16 = 4 VGPRs (MFMA A/B frag)

constexpr int Ntok   = 4096;
constexpr int Cdim   = 768;
constexpr int Hn     = 6;
constexpr int HD     = 128;
constexpr int QKcols = 1536;   // 2*Cdim
constexpr int NTRI   = 21;     // 6x6 upper-triangular tiles
constexpr int SPLITK = 4;      // gram split-K

#define AS1 __attribute__((address_space(1)))
#define AS3 __attribute__((address_space(3)))

__device__ inline void gload_lds16(const bf16* g, bf16* l) {
    __builtin_amdgcn_global_load_lds((const AS1 void*)g, (AS3 void*)l, 16, 0, 0);
}

__device__ inline int4 cvt8_f32_to_bf16(const float* p) {
    const float4 a0 = *reinterpret_cast<const float4*>(p);
    const float4 a1 = *reinterpret_cast<const float4*>(p + 4);
    union { int4 i; bf16 h[8]; } u;
    u.h[0] = __float2bfloat16(a0.x); u.h[1] = __float2bfloat16(a0.y);
    u.h[2] = __float2bfloat16(a0.z); u.h[3] = __float2bfloat16(a0.w);
    u.h[4] = __float2bfloat16(a1.x); u.h[5] = __float2bfloat16(a1.y);
    u.h[6] = __float2bfloat16(a1.z); u.h[7] = __float2bfloat16(a1.w);
    return u.i;
}

// ---------------------------------------------------------------------------
// fp32 -> bf16 bulk convert (y). 8 elems/thread.
// ---------------------------------------------------------------------------
__global__ __launch_bounds__(256) void cvt_kernel(const float* __restrict__ in,
                                                  bf16* __restrict__ out) {
    const size_t i = ((size_t)blockIdx.x * 256 + threadIdx.x) * 8;
    *reinterpret_cast<int4*>(out + i) = cvt8_f32_to_bf16(in + i);
}

// ---------------------------------------------------------------------------
// Transpose + cast: W[K][N] fp32 -> Wt[N][K] bf16
// ---------------------------------------------------------------------------
__global__ void transpose_kernel(const float* __restrict__ W, bf16* __restrict__ Wt,
                                 int K, int N) {
    __shared__ bf16 tile[32][33];
    const int n0 = blockIdx.x * 32, k0 = blockIdx.y * 32;
    const int tx = threadIdx.x, ty = threadIdx.y;      // blockDim (32,8)
    for (int i = 0; i < 32; i += 8)
        tile[ty + i][tx] = __float2bfloat16(W[(size_t)(k0 + ty + i) * N + n0 + tx]);
    __syncthreads();
    for (int i = 0; i < 32; i += 8)
        Wt[(size_t)(n0 + ty + i) * K + k0 + tx] = tile[tx][ty + i];
}

// ---------------------------------------------------------------------------
// x [b][n][c] fp32 -> xT [b][c][n] bf16.  64n x 32c tiles, block 256 flat.
// ---------------------------------------------------------------------------
__global__ __launch_bounds__(256) void transpose_x(const float* __restrict__ x,
                                                   bf16* __restrict__ xT) {
    __shared__ bf16 tile[64][34];          // 17-stride banks: 2-way max (free)
    const int b = blockIdx.z, n0 = blockIdx.y * 64, c0 = blockIdx.x * 32;
    const int tid = threadIdx.x;
    const int c_r = tid & 31, n_r = tid >> 5;          // 8 n-rows per iter
    const float* xp = x + ((size_t)b * Ntok + n0) * Cdim + c0;
#pragma unroll
    for (int i = 0; i < 64; i += 8)
        tile[n_r + i][c_r] = __float2bfloat16(xp[(size_t)(n_r + i) * Cdim + c_r]);
    __syncthreads();
    const int n_w = tid & 63, c_w = tid >> 6;          // 4 c-cols per iter
    bf16* op = xT + ((size_t)b * Cdim + c0) * Ntok + n0;
#pragma unroll
    for (int i = 0; i < 32; i += 4)
        op[(size_t)(c_w + i) * Ntok + n_w] = tile[n_w][c_w + i];
}

// ---------------------------------------------------------------------------
// GEMM: C[M][N] = A[M][K] @ Bt[N][K]^T (+bias). bf16 in, fp32 accum.
// Batched via blockIdx.z with element strides a_bs / bt_bs / c_bs.
// ---------------------------------------------------------------------------
template <bool C_F32, bool BIAS>
__global__ __launch_bounds__(256) void gemm_bt(const bf16* __restrict__ A,
                                               const bf16* __restrict__ Bt,
                                               const float* __restrict__ bias,
                                               void* __restrict__ Cv,
                                               int N, int K,
                                               size_t a_bs, size_t bt_bs, size_t c_bs) {
    __shared__ bf16 As[128 * 32];
    __shared__ bf16 Bs[128 * 32];

    A  += (size_t)blockIdx.z * a_bs;
    Bt += (size_t)blockIdx.z * bt_bs;
    const int m0   = blockIdx.y * 128, n0 = blockIdx.x * 128;
    const int tid  = threadIdx.x;
    const int wave = tid >> 6, lane = tid & 63;
    const int wq   = wave >> 1, wr = wave & 1;
    const int lm   = lane & 15, quad = lane >> 4;

    const int srow = tid >> 2, scol = (tid & 3) * 8;
    const bf16* Ag = A  + (size_t)(m0 + srow) * K + scol;
    const bf16* Bg = Bt + (size_t)(n0 + srow) * K + scol;
    bf16* Al0 = &As[srow * 32 + scol];
    bf16* Al1 = &As[(64 + srow) * 32 + scol];
    bf16* Bl0 = &Bs[srow * 32 + scol];
    bf16* Bl1 = &Bs[(64 + srow) * 32 + scol];

    f32x4 acc[4][4] = {};

    for (int k0 = 0; k0 < K; k0 += 32) {
        __syncthreads();
        gload_lds16(Ag + k0,                  Al0);
        gload_lds16(Ag + (size_t)64 * K + k0, Al1);
        gload_lds16(Bg + k0,                  Bl0);
        gload_lds16(Bg + (size_t)64 * K + k0, Bl1);
        __syncthreads();

        bf16x8 af[4], bfr[4];
#pragma unroll
        for (int t = 0; t < 4; t++) {
            af[t]  = *reinterpret_cast<const bf16x8*>(&As[(wq * 64 + t * 16 + lm) * 32 + quad * 8]);
            bfr[t] = *reinterpret_cast<const bf16x8*>(&Bs[(wr * 64 + t * 16 + lm) * 32 + quad * 8]);
        }
#pragma unroll
        for (int mt = 0; mt < 4; mt++)
#pragma unroll
            for (int nt = 0; nt < 4; nt++)
                acc[mt][nt] = __builtin_amdgcn_mfma_f32_16x16x32_bf16(af[mt], bfr[nt], acc[mt][nt], 0, 0, 0);
    }

    const int cm = m0 + wq * 64, cn = n0 + wr * 64;
#pragma unroll
    for (int mt = 0; mt < 4; mt++) {
#pragma unroll
        for (int nt = 0; nt < 4; nt++) {
            const int col = cn + nt * 16 + lm;
            const float bv = BIAS ? bias[col] : 0.0f;
#pragma unroll
            for (int r = 0; r < 4; r++) {
                const int row = cm + mt * 16 + quad * 4 + r;
                if constexpr (C_F32)
                    ((float*)Cv + (size_t)blockIdx.z * c_bs)[(size_t)row * N + col] = acc[mt][nt][r] + bv;
                else
                    ((bf16*)Cv + (size_t)blockIdx.z * c_bs)[(size_t)row * N + col] = __float2bfloat16(acc[mt][nt][r] + bv);
            }
        }
    }
}

// ---------------------------------------------------------------------------
// Gram split-K: partial[(t*8+b)*S+s][128][128] = xT_b[c-panel] @ xT_b[d-panel]^T
// over token slice s. grid (21, 8, S). m97 staging (global_load_lds).
// ---------------------------------------------------------------------------
__global__ __launch_bounds__(256) void gram_k(const bf16* __restrict__ xT,
                                              float* __restrict__ partial) {
    __shared__ bf16 As[128 * 32];
    __shared__ bf16 Bs[128 * 32];

    int ci = 0, rem = blockIdx.x, rowlen = 6;
    while (rem >= rowlen) { rem -= rowlen; rowlen--; ci++; }
    const int di = ci + rem;
    const int b = blockIdx.y, s = blockIdx.z;
    const int c0 = ci * 128, d0 = di * 128;

    const int tid  = threadIdx.x;
    const int wave = tid >> 6, lane = tid & 63;
    const int wq   = wave >> 1, wr = wave & 1;
    const int lm   = lane & 15, quad = lane >> 4;

    const int srow = tid >> 2, scol = (tid & 3) * 8;
    const size_t base = (size_t)b * Cdim * Ntok + (size_t)s * (Ntok / SPLITK);
    const bf16* Ag = xT + base + (size_t)(c0 + srow) * Ntok + scol;
    const bf16* Bg = xT + base + (size_t)(d0 + srow) * Ntok + scol;
    bf16* Al0 = &As[srow * 32 + scol];
    bf16* Al1 = &As[(64 + srow) * 32 + scol];
    bf16* Bl0 = &Bs[srow * 32 + scol];
    bf16* Bl1 = &Bs[(64 + srow) * 32 + scol];

    f32x4 acc[4][4] = {};

    for (int k0 = 0; k0 < Ntok / SPLITK; k0 += 32) {
        __syncthreads();
        gload_lds16(Ag + k0,                     Al0);
        gload_lds16(Ag + (size_t)64 * Ntok + k0, Al1);
        gload_lds16(Bg + k0,                     Bl0);
        gload_lds16(Bg + (size_t)64 * Ntok + k0, Bl1);
        __syncthreads();

        bf16x8 af[4], bfr[4];
#pragma unroll
        for (int t = 0; t < 4; t++) {
            af[t]  = *reinterpret_cast<const bf16x8*>(&As[(wq * 64 + t * 16 + lm) * 32 + quad * 8]);
            bfr[t] = *reinterpret_cast<const bf16x8*>(&Bs[(wr * 64 + t * 16 + lm) * 32 + quad * 8]);
        }
#pragma unroll
        for (int mt = 0; mt < 4; mt++)
#pragma unroll
            for (int nt = 0; nt < 4; nt++)
                acc[mt][nt] = __builtin_amdgcn_mfma_f32_16x16x32_bf16(af[mt], bfr[nt], acc[mt][nt], 0, 0, 0);
    }

    float* pp = partial + (((size_t)blockIdx.x * 8 + b) * SPLITK + s) * 16384;
#pragma unroll
    for (int mt = 0; mt < 4; mt++)
#pragma unroll
        for (int nt = 0; nt < 4; nt++)
#pragma unroll
            for (int r = 0; r < 4; r++)
                pp[(size_t)(wq * 64 + mt * 16 + quad * 4 + r) * 128 + wr * 64 + nt * 16 + lm] = acc[mt][nt][r];
}

// ---------------------------------------------------------------------------
// Reduce split-K partials -> G bf16 [b][768][768], with symmetric mirror.
// grid (21, 8), block 256.
// ---------------------------------------------------------------------------
__global__ __launch_bounds__(256) void gram_reduce(const float* __restrict__ partial,
                                                   bf16* __restrict__ G) {
    int ci = 0, rem = blockIdx.x, rowlen = 6;
    while (rem >= rowlen) { rem -= rowlen; rowlen--; ci++; }
    const int di = ci + rem, b = blockIdx.y;
    const int c0 = ci * 128, d0 = di * 128;
    const float* p0 = partial + ((size_t)blockIdx.x * 8 + b) * SPLITK * 16384;
    bf16* Gb = G + (size_t)b * Cdim * Cdim;
    const int tid = threadIdx.x;

    for (int i = 0; i < 16; i++) {
        const int off = i * 1024 + tid * 4;
        float4 v = *reinterpret_cast<const float4*>(p0 + off);
#pragma unroll
        for (int s2 = 1; s2 < SPLITK; s2++) {
            const float4 u = *reinterpret_cast<const float4*>(p0 + (size_t)s2 * 16384 + off);
            v.x += u.x; v.y += u.y; v.z += u.z; v.w += u.w;
        }
        const int c = off >> 7, d = off & 127;
        union { uint2 u2; bf16 h[4]; } pk;
        pk.h[0] = __float2bfloat16(v.x); pk.h[1] = __float2bfloat16(v.y);
        pk.h[2] = __float2bfloat16(v.z); pk.h[3] = __float2bfloat16(v.w);
        *reinterpret_cast<uint2*>(&Gb[(size_t)(c0 + c) * Cdim + d0 + d]) = pk.u2;
        if (ci != di) {
#pragma unroll
            for (int jj = 0; jj < 4; jj++)
                Gb[(size_t)(d0 + d + jj) * Cdim + c0 + c] = pk.h[jj];
        }
    }
}

// ---------------------------------------------------------------------------
// Diag norms: invn[b][col] = 1/max(sqrt(sum_r Wtq[col][r]*GWT[b][col][r]), eps)
// grid (48, 8): 32 cols/block, 8 threads per col. Coalesced row-dots.
// ---------------------------------------------------------------------------
__global__ __launch_bounds__(256) void diag_kernel(const bf16* __restrict__ Wtq,
                                                   const bf16* __restrict__ GWT,
                                                   float* __restrict__ invn) {
    const int b = blockIdx.y;
    const int col = blockIdx.x * 32 + (threadIdx.x >> 3);
    const int sub = threadIdx.x & 7;
    const bf16* w = Wtq + (size_t)col * Cdim + sub * 8;
    const bf16* g = GWT + ((size_t)b * QKcols + col) * Cdim + sub * 8;
    float s = 0.0f;
    for (int i = 0; i < 12; i++) {
        bf16 wv[8], gv[8];
        *reinterpret_cast<int4*>(wv) = *reinterpret_cast<const int4*>(w + i * 64);
        *reinterpret_cast<int4*>(gv) = *reinterpret_cast<const int4*>(g + i * 64);
#pragma unroll
        for (int u = 0; u < 8; u++) s += (float)wv[u] * (float)gv[u];
    }
    s += __shfl_xor(s, 1, 64);
    s += __shfl_xor(s, 2, 64);
    s += __shfl_xor(s, 4, 64);
    if (sub == 0)
        invn[(size_t)b * QKcols + col] = 1.0f / fmaxf(sqrtf(fmaxf(s, 0.0f)), 1e-12f);
}

// ---------------------------------------------------------------------------
// Logits + softmax per (b,h). grid 48. Fragment-direct loads (no LDS staging).
//   L[c,d] = (sum_r Wtq[qoff+c][r]*GWT[b][koff+d][r]) * invq[c]*invk[d]*temp
//   attnT[bh][d][c] = softmax_d(L)[c][d]
// ---------------------------------------------------------------------------
__global__ __launch_bounds__(256) void head_kernel(const bf16* __restrict__ GWT,
                                                   const bf16* __restrict__ Wtq,
                                                   const float* __restrict__ invn,
                                                   const float* __restrict__ temp,
                                                   bf16* __restrict__ attnT) {
    constexpr int LDP = 136;
    __shared__ bf16 At[HD * LDP];               // attn^T staging, 34.8 KB

    const int bh = blockIdx.x, b = bh / Hn, h = bh % Hn;
    const int tid = threadIdx.x, wave = tid >> 6, lane = tid & 63;
    const int lm = lane & 15, quad = lane >> 4;
    const int qoff = h * HD, koff = Cdim + h * HD;
    const float th = temp[h];
    const float* invq = invn + (size_t)b * QKcols + qoff;
    const float* invk = invn + (size_t)b * QKcols + koff;

    f32x4 acc[2][8] = {};
    const bf16* Aq = Wtq + (size_t)(qoff + wave * 32 + lm) * Cdim + quad * 8;
    const bf16* Bk = GWT + ((size_t)b * QKcols + koff + lm) * Cdim + quad * 8;
    for (int r0 = 0; r0 < Cdim; r0 += 32) {
        bf16x8 aq[2], bk[8];
#pragma unroll
        for (int mt = 0; mt < 2; mt++)
            aq[mt] = *reinterpret_cast<const bf16x8*>(Aq + (size_t)mt * 16 * Cdim + r0);
#pragma unroll
        for (int dt = 0; dt < 8; dt++)
            bk[dt] = *reinterpret_cast<const bf16x8*>(Bk + (size_t)dt * 16 * Cdim + r0);
#pragma unroll
        for (int mt = 0; mt < 2; mt++)
#pragma unroll
            for (int dt = 0; dt < 8; dt++)
                acc[mt][dt] = __builtin_amdgcn_mfma_f32_16x16x32_bf16(aq[mt], bk[dt], acc[mt][dt], 0, 0, 0);
    }

    float ikv[8];
#pragma unroll
    for (int dt = 0; dt < 8; dt++) ikv[dt] = invk[dt * 16 + lm] * th;
#pragma unroll
    for (int mt = 0; mt < 2; mt++) {
#pragma unroll
        for (int r = 0; r < 4; r++) {
            const int c = wave * 32 + mt * 16 + quad * 4 + r;
            const float iq = invq[c];
            float v[8], m = -1e30f;
#pragma unroll
            for (int dt = 0; dt < 8; dt++) { v[dt] = acc[mt][dt][r] * iq * ikv[dt]; m = fmaxf(m, v[dt]); }
            m = fmaxf(m, __shfl_xor(m, 1, 64));
            m = fmaxf(m, __shfl_xor(m, 2, 64));
            m = fmaxf(m, __shfl_xor(m, 4, 64));
            m = fmaxf(m, __shfl_xor(m, 8, 64));
            float sum = 0.0f;
#pragma unroll
            for (int dt = 0; dt < 8; dt++) { v[dt] = __expf(v[dt] - m); sum += v[dt]; }
            sum += __shfl_xor(sum, 1, 64);
            sum += __shfl_xor(sum, 2, 64);
            sum += __shfl_xor(sum, 4, 64);
            sum += __shfl_xor(sum, 8, 64);
            const float inv = 1.0f / sum;
#pragma unroll
            for (int dt = 0; dt < 8; dt++)
                At[(dt * 16 + lm) * LDP + c] = __float2bfloat16(v[dt] * inv);
        }
    }
    __syncthreads();

    // coalesced dump: attnT[bh][d][c]
#pragma unroll
    for (int i = 0; i < 8; i++) {
        const int idx = tid + 256 * i;              // 0..2047
        const int d = idx >> 4, c8 = (idx & 15) * 8;
        const bf16x8 v = *reinterpret_cast<const bf16x8*>(&At[d * LDP + c8]);
        *reinterpret_cast<bf16x8*>(&attnT[((size_t)bh * HD + d) * HD + c8]) = v;
    }
}

// ---------------------------------------------------------------------------
// Weff fold: WeffT[b][j][h*128+d] = sum_c attnT[bh][d][c] * Wtp[j][h*128+c]
// grid (6 j-tiles, 48 bh). Fragment-direct, no LDS, no syncs.
// ---------------------------------------------------------------------------
__global__ __launch_bounds__(256) void fold_kernel(const bf16* __restrict__ attnT,
                                                   const bf16* __restrict__ Wtp,
                                                   bf16* __restrict__ WeffT) {
    const int j0 = blockIdx.x * 128, bh = blockIdx.y, b = bh / Hn, h = bh % Hn;
    const int tid = threadIdx.x, wave = tid >> 6, lane = tid & 63;
    const int lm = lane & 15, quad = lane >> 4;

    f32x4 acc[2][8] = {};
    const bf16* Ap = Wtp + (size_t)(j0 + wave * 32 + lm) * Cdim + h * HD + quad * 8;
    const bf16* Bd = attnT + ((size_t)bh * HD + lm) * HD + quad * 8;
#pragma unroll
    for (int ks = 0; ks < HD; ks += 32) {
        bf16x8 aw[2], bd[8];
#pragma unroll
        for (int mt = 0; mt < 2; mt++)
            aw[mt] = *reinterpret_cast<const bf16x8*>(Ap + (size_t)mt * 16 * Cdim + ks);
#pragma unroll
        for (int dt = 0; dt < 8; dt++)
            bd[dt] = *reinterpret_cast<const bf16x8*>(Bd + (size_t)dt * 16 * HD + ks);
#pragma unroll
        for (int mt = 0; mt < 2; mt++)
#pragma unroll
            for (int dt = 0; dt < 8; dt++)
                acc[mt][dt] = __builtin_amdgcn_mfma_f32_16x16x32_bf16(aw[mt], bd[dt], acc[mt][dt], 0, 0, 0);
    }

    bf16* Wo = WeffT + (size_t)b * Cdim * Cdim + h * HD;
#pragma unroll
    for (int mt = 0; mt < 2; mt++)
#pragma unroll
        for (int dt = 0; dt < 8; dt++)
#pragma unroll
            for (int r = 0; r < 4; r++)
                Wo[(size_t)(j0 + wave * 32 + mt * 16 + quad * 4 + r) * Cdim + dt * 16 + lm] =
                    __float2bfloat16(acc[mt][dt][r]);
}

// ---------------------------------------------------------------------------
extern "C" void kernel_launch(void* const* d_in, const int* in_sizes, int n_in,
                              void* d_out, int out_size, void* d_ws, size_t ws_size,
                              hipStream_t stream) {
    const float* x     = (const float*)d_in[0];
    const float* y     = (const float*)d_in[1];
    const float* Wqkv  = (const float*)d_in[2];
    const float* temp  = (const float*)d_in[3];
    const float* Wproj = (const float*)d_in[4];
    const float* bproj = (const float*)d_in[5];
    float* out = (float*)d_out;

    char* ws = (char*)d_ws;
    size_t o = 0;
    bf16*  xT      = (bf16*)(ws + o); o += (size_t)8 * Cdim * Ntok * 2;        // 50.3 MB
    bf16*  yb      = (bf16*)(ws + o); o += (size_t)8 * Ntok * Cdim * 2;        // 50.3 MB
    float* partial = (float*)(ws + o); o += (size_t)NTRI * 8 * SPLITK * 16384 * 4; // 44.0 MB
    bf16*  G       = (bf16*)(ws + o); o += (size_t)8 * Cdim * Cdim * 2;        //  9.4 MB
    bf16*  GWT     = (bf16*)(ws + o); o += (size_t)8 * QKcols * Cdim * 2;      // 18.9 MB
    bf16*  WeffT   = (bf16*)(ws + o); o += (size_t)8 * Cdim * Cdim * 2;        //  9.4 MB
    bf16*  Wt_qkv  = (bf16*)(ws + o); o += (size_t)QKcols * Cdim * 2;
    bf16*  Wt_proj = (bf16*)(ws + o); o += (size_t)Cdim * Cdim * 2;
    float* invn    = (float*)(ws + o); o += (size_t)8 * QKcols * 4;
    bf16*  attnT   = (bf16*)(ws + o); o += (size_t)48 * HD * HD * 2;

    dim3 tb(32, 8);
    transpose_kernel<<<dim3(QKcols / 32, Cdim / 32), tb, 0, stream>>>(Wqkv, Wt_qkv, Cdim, QKcols);
    transpose_kernel<<<dim3(Cdim / 32, Cdim / 32), tb, 0, stream>>>(Wproj, Wt_proj, Cdim, Cdim);

    transpose_x<<<dim3(Cdim / 32, Ntok / 64, 8), 256, 0, stream>>>(x, xT);
    cvt_kernel<<<12288, 256, 0, stream>>>(y, yb);

    // Gram split-K + reduce: G_b = x_b^T x_b (bf16, symmetric)
    gram_k<<<dim3(NTRI, 8, SPLITK), 256, 0, stream>>>(xT, partial);
    gram_reduce<<<dim3(NTRI, 8), 256, 0, stream>>>(partial, G);

    // GWT[b][j][r] = (G_b @ W_qkv)^T = W_qkv^T G_b  (G symmetric)
    gemm_bt<false, false><<<dim3(Cdim / 128, QKcols / 128, 8), 256, 0, stream>>>(
        Wt_qkv, G, nullptr, GWT, Cdim, Cdim,
        0, (size_t)Cdim * Cdim, (size_t)QKcols * Cdim);

    diag_kernel<<<dim3(QKcols / 32, 8), 256, 0, stream>>>(Wt_qkv, GWT, invn);
    head_kernel<<<48, 256, 0, stream>>>(GWT, Wt_qkv, invn, temp, attnT);
    fold_kernel<<<dim3(Cdim / 128, 48), 256, 0, stream>>>(attnT, Wt_proj, WeffT);

    // out = y_b @ Weff_b + b_proj   (per-batch B), M=4096/batch
    gemm_bt<true, true><<<dim3(Cdim / 128, Ntok / 128, 8), 256, 0, stream>>>(
        yb, WeffT, bproj, out, Cdim, Cdim,
        (size_t)Ntok * Cdim, (size_t)Cdim * Cdim, (size_t)Ntok * Cdim);
}

// Round 3
// 460.317 us; speedup vs baseline: 1.2308x; 1.0633x over previous
//
#include <hip/hip_runtime.h>
#include <hip/hip_bf16.h>

using bf16 = __hip_bfloat16;
typedef __attribute__((ext_vector_type(4))) float f32x4;
typedef __attribute__((ext_vector_type(8))) short bf16x8;   // 8 bf16 = 4 VGPRs (MFMA A/B frag)

constexpr int Ntok   = 4096;
constexpr int Cdim   = 768;
constexpr int Hn     = 6;
constexpr int HD     = 128;
constexpr int QKcols = 1536;   // 2*Cdim
constexpr int NTRI   = 21;     // 6x6 upper-triangular tiles
constexpr int SPLITK = 4;      // gram split-K

#define AS1 __attribute__((address_space(1)))
#define AS3 __attribute__((address_space(3)))

__device__ inline void gload_lds16(const bf16* g, bf16* l) {
    __builtin_amdgcn_global_load_lds((const AS1 void*)g, (AS3 void*)l, 16, 0, 0);
}

__device__ inline int4 cvt8_f32_to_bf16(const float* p) {
    const float4 a0 = *reinterpret_cast<const float4*>(p);
    const float4 a1 = *reinterpret_cast<const float4*>(p + 4);
    union { int4 i; bf16 h[8]; } u;
    u.h[0] = __float2bfloat16(a0.x); u.h[1] = __float2bfloat16(a0.y);
    u.h[2] = __float2bfloat16(a0.z); u.h[3] = __float2bfloat16(a0.w);
    u.h[4] = __float2bfloat16(a1.x); u.h[5] = __float2bfloat16(a1.y);
    u.h[6] = __float2bfloat16(a1.z); u.h[7] = __float2bfloat16(a1.w);
    return u.i;
}

// ---------------------------------------------------------------------------
// All transposes in ONE launch: src[R][C] fp32 -> dst[C][R] bf16, 64r x 32c tiles.
//   ids [0,12288):        x   (8 batches, R=4096, C=768)
//   ids [12288,12864):    Wqkv (R=768, C=1536)
//   ids [12864,13152):    Wproj(R=768, C=768)
// ---------------------------------------------------------------------------
__global__ __launch_bounds__(256) void transpose_all(const float* __restrict__ x,   bf16* __restrict__ xT,
                                                     const float* __restrict__ Wqkv, bf16* __restrict__ Wtq,
                                                     const float* __restrict__ Wproj, bf16* __restrict__ Wtp) {
    __shared__ bf16 tile[64][34];
    const int id = blockIdx.x;
    const float* src; bf16* dst; int R, C, r0, c0;
    if (id < 12288) {
        const int b = id / 1536, rem = id % 1536;
        r0 = (rem & 63) * 64; c0 = (rem >> 6) * 32;
        R = Ntok; C = Cdim;
        src = x + (size_t)b * Ntok * Cdim; dst = xT + (size_t)b * Cdim * Ntok;
    } else if (id < 12864) {
        const int rem = id - 12288;
        r0 = (rem % 12) * 64; c0 = (rem / 12) * 32;
        R = Cdim; C = QKcols; src = Wqkv; dst = Wtq;
    } else {
        const int rem = id - 12864;
        r0 = (rem % 12) * 64; c0 = (rem / 12) * 32;
        R = Cdim; C = Cdim; src = Wproj; dst = Wtp;
    }
    const int tid = threadIdx.x;
    const int c_r = tid & 31, n_r = tid >> 5;
    const float* sp = src + (size_t)(r0 + n_r) * C + c0 + c_r;
#pragma unroll
    for (int i = 0; i < 64; i += 8)
        tile[n_r + i][c_r] = __float2bfloat16(sp[(size_t)i * C]);
    __syncthreads();
    const int n_w = tid & 63, c_w = tid >> 6;
#pragma unroll
    for (int i = 0; i < 32; i += 4)
        dst[(size_t)(c0 + c_w + i) * R + r0 + n_w] = tile[n_w][c_w + i];
}

// ---------------------------------------------------------------------------
// GEMM: C[M][N] = A[M][K] @ Bt[N][K]^T. bf16 in, fp32 accum, bf16 out.
// Batched via blockIdx.z with element strides a_bs / bt_bs / c_bs.
// ---------------------------------------------------------------------------
__global__ __launch_bounds__(256) void gemm_bt(const bf16* __restrict__ A,
                                               const bf16* __restrict__ Bt,
                                               bf16* __restrict__ Cv,
                                               int N, int K,
                                               size_t a_bs, size_t bt_bs, size_t c_bs) {
    __shared__ bf16 As[128 * 32];
    __shared__ bf16 Bs[128 * 32];

    A  += (size_t)blockIdx.z * a_bs;
    Bt += (size_t)blockIdx.z * bt_bs;
    const int m0   = blockIdx.y * 128, n0 = blockIdx.x * 128;
    const int tid  = threadIdx.x;
    const int wave = tid >> 6, lane = tid & 63;
    const int wq   = wave >> 1, wr = wave & 1;
    const int lm   = lane & 15, quad = lane >> 4;

    const int srow = tid >> 2, scol = (tid & 3) * 8;
    const bf16* Ag = A  + (size_t)(m0 + srow) * K + scol;
    const bf16* Bg = Bt + (size_t)(n0 + srow) * K + scol;
    bf16* Al0 = &As[srow * 32 + scol];
    bf16* Al1 = &As[(64 + srow) * 32 + scol];
    bf16* Bl0 = &Bs[srow * 32 + scol];
    bf16* Bl1 = &Bs[(64 + srow) * 32 + scol];

    f32x4 acc[4][4] = {};

    for (int k0 = 0; k0 < K; k0 += 32) {
        __syncthreads();
        gload_lds16(Ag + k0,                  Al0);
        gload_lds16(Ag + (size_t)64 * K + k0, Al1);
        gload_lds16(Bg + k0,                  Bl0);
        gload_lds16(Bg + (size_t)64 * K + k0, Bl1);
        __syncthreads();

        bf16x8 af[4], bfr[4];
#pragma unroll
        for (int t = 0; t < 4; t++) {
            af[t]  = *reinterpret_cast<const bf16x8*>(&As[(wq * 64 + t * 16 + lm) * 32 + quad * 8]);
            bfr[t] = *reinterpret_cast<const bf16x8*>(&Bs[(wr * 64 + t * 16 + lm) * 32 + quad * 8]);
        }
#pragma unroll
        for (int mt = 0; mt < 4; mt++)
#pragma unroll
            for (int nt = 0; nt < 4; nt++)
                acc[mt][nt] = __builtin_amdgcn_mfma_f32_16x16x32_bf16(af[mt], bfr[nt], acc[mt][nt], 0, 0, 0);
    }

    bf16* Cb = Cv + (size_t)blockIdx.z * c_bs;
    const int cm = m0 + wq * 64, cn = n0 + wr * 64;
#pragma unroll
    for (int mt = 0; mt < 4; mt++)
#pragma unroll
        for (int nt = 0; nt < 4; nt++) {
            const int col = cn + nt * 16 + lm;
#pragma unroll
            for (int r = 0; r < 4; r++)
                Cb[(size_t)(cm + mt * 16 + quad * 4 + r) * N + col] = __float2bfloat16(acc[mt][nt][r]);
        }
}

// ---------------------------------------------------------------------------
// Gram split-K, XCD-chunked 1D grid (672 = 8 batches x 84):
//   b = bid&7 (== XCD under round-robin), rem = bid>>3, tile t = rem%21, s = rem/21
// partial[(t*8+b)*S+s][128][128] = xT_b[c-panel] @ xT_b[d-panel]^T over token slice s.
// ---------------------------------------------------------------------------
__global__ __launch_bounds__(256) void gram_k(const bf16* __restrict__ xT,
                                              float* __restrict__ partial) {
    __shared__ bf16 As[128 * 32];
    __shared__ bf16 Bs[128 * 32];

    const int bid = blockIdx.x;
    const int b = bid & 7, rem = bid >> 3;
    const int t = rem % 21, s = rem / 21;
    int ci = 0, trem = t, rowlen = 6;
    while (trem >= rowlen) { trem -= rowlen; rowlen--; ci++; }
    const int di = ci + trem;
    const int c0 = ci * 128, d0 = di * 128;

    const int tid  = threadIdx.x;
    const int wave = tid >> 6, lane = tid & 63;
    const int wq   = wave >> 1, wr = wave & 1;
    const int lm   = lane & 15, quad = lane >> 4;

    const int srow = tid >> 2, scol = (tid & 3) * 8;
    const size_t base = (size_t)b * Cdim * Ntok + (size_t)s * (Ntok / SPLITK);
    const bf16* Ag = xT + base + (size_t)(c0 + srow) * Ntok + scol;
    const bf16* Bg = xT + base + (size_t)(d0 + srow) * Ntok + scol;
    bf16* Al0 = &As[srow * 32 + scol];
    bf16* Al1 = &As[(64 + srow) * 32 + scol];
    bf16* Bl0 = &Bs[srow * 32 + scol];
    bf16* Bl1 = &Bs[(64 + srow) * 32 + scol];

    f32x4 acc[4][4] = {};

    for (int k0 = 0; k0 < Ntok / SPLITK; k0 += 32) {
        __syncthreads();
        gload_lds16(Ag + k0,                     Al0);
        gload_lds16(Ag + (size_t)64 * Ntok + k0, Al1);
        gload_lds16(Bg + k0,                     Bl0);
        gload_lds16(Bg + (size_t)64 * Ntok + k0, Bl1);
        __syncthreads();

        bf16x8 af[4], bfr[4];
#pragma unroll
        for (int u = 0; u < 4; u++) {
            af[u]  = *reinterpret_cast<const bf16x8*>(&As[(wq * 64 + u * 16 + lm) * 32 + quad * 8]);
            bfr[u] = *reinterpret_cast<const bf16x8*>(&Bs[(wr * 64 + u * 16 + lm) * 32 + quad * 8]);
        }
#pragma unroll
        for (int mt = 0; mt < 4; mt++)
#pragma unroll
            for (int nt = 0; nt < 4; nt++)
                acc[mt][nt] = __builtin_amdgcn_mfma_f32_16x16x32_bf16(af[mt], bfr[nt], acc[mt][nt], 0, 0, 0);
    }

    float* pp = partial + (((size_t)t * 8 + b) * SPLITK + s) * 16384;
#pragma unroll
    for (int mt = 0; mt < 4; mt++)
#pragma unroll
        for (int nt = 0; nt < 4; nt++)
#pragma unroll
            for (int r = 0; r < 4; r++)
                pp[(size_t)(wq * 64 + mt * 16 + quad * 4 + r) * 128 + wr * 64 + nt * 16 + lm] = acc[mt][nt][r];
}

// ---------------------------------------------------------------------------
// Reduce split-K partials -> G bf16 [b][768][768], with symmetric mirror.
// grid (21, 8), block 256.
// ---------------------------------------------------------------------------
__global__ __launch_bounds__(256) void gram_reduce(const float* __restrict__ partial,
                                                   bf16* __restrict__ G) {
    int ci = 0, rem = blockIdx.x, rowlen = 6;
    while (rem >= rowlen) { rem -= rowlen; rowlen--; ci++; }
    const int di = ci + rem, b = blockIdx.y;
    const int c0 = ci * 128, d0 = di * 128;
    const float* p0 = partial + ((size_t)blockIdx.x * 8 + b) * SPLITK * 16384;
    bf16* Gb = G + (size_t)b * Cdim * Cdim;
    const int tid = threadIdx.x;

    for (int i = 0; i < 16; i++) {
        const int off = i * 1024 + tid * 4;
        float4 v = *reinterpret_cast<const float4*>(p0 + off);
#pragma unroll
        for (int s2 = 1; s2 < SPLITK; s2++) {
            const float4 u = *reinterpret_cast<const float4*>(p0 + (size_t)s2 * 16384 + off);
            v.x += u.x; v.y += u.y; v.z += u.z; v.w += u.w;
        }
        const int c = off >> 7, d = off & 127;
        union { uint2 u2; bf16 h[4]; } pk;
        pk.h[0] = __float2bfloat16(v.x); pk.h[1] = __float2bfloat16(v.y);
        pk.h[2] = __float2bfloat16(v.z); pk.h[3] = __float2bfloat16(v.w);
        *reinterpret_cast<uint2*>(&Gb[(size_t)(c0 + c) * Cdim + d0 + d]) = pk.u2;
        if (ci != di) {
#pragma unroll
            for (int jj = 0; jj < 4; jj++)
                Gb[(size_t)(d0 + d + jj) * Cdim + c0 + c] = pk.h[jj];
        }
    }
}

// ---------------------------------------------------------------------------
// Per-(b,h) merged head: diag norms + logits + softmax + Weff fold. grid 48.
//   invq[c] = 1/max(sqrt(sum_r Wtq[qoff+c][r]*GWT[b][qoff+c][r]), eps)   (invk same)
//   L[c,d]  = (sum_r Wtq[qoff+c][r]*GWT[b][koff+d][r]) * invq[c]*invk[d]*temp
//   At[d][c]= softmax_d(L)[c][d]    (in-register softmax)
//   WeffT[b][j][h*128+d] = sum_c At[d][c] * Wtp[j][h*128+c]
// ---------------------------------------------------------------------------
__global__ __launch_bounds__(256) void head_all(const bf16* __restrict__ GWT,
                                                const bf16* __restrict__ Wtq,
                                                const bf16* __restrict__ Wtp,
                                                const float* __restrict__ temp,
                                                bf16* __restrict__ WeffT) {
    constexpr int LDP = 136;
    __shared__ bf16 At[HD * LDP];               // attn^T, 34.8 KB
    __shared__ float invq[HD], invk[HD];

    const int bh = blockIdx.x, b = bh / Hn, h = bh % Hn;
    const int tid = threadIdx.x, wave = tid >> 6, lane = tid & 63;
    const int lm = lane & 15, quad = lane >> 4;
    const int qoff = h * HD, koff = Cdim + h * HD;
    const float th = temp[h];

    // ---- phase 1: diag norms (8 threads/col, 32 cols/pass, 8 passes) ----
    {
        const int coli = tid >> 3, sub = tid & 7;
#pragma unroll
        for (int pass = 0; pass < 8; pass++) {
            const int cl = pass * 32 + coli;          // 0..255 (128 q, 128 k)
            const int isk = cl >> 7;
            const int col = (isk ? koff : qoff) + (cl & 127);
            const bf16* w = Wtq + (size_t)col * Cdim + sub * 8;
            const bf16* g = GWT + ((size_t)b * QKcols + col) * Cdim + sub * 8;
            float s = 0.0f;
#pragma unroll
            for (int i = 0; i < 12; i++) {
                bf16 wv[8], gv[8];
                *reinterpret_cast<int4*>(wv) = *reinterpret_cast<const int4*>(w + i * 64);
                *reinterpret_cast<int4*>(gv) = *reinterpret_cast<const int4*>(g + i * 64);
#pragma unroll
                for (int u = 0; u < 8; u++) s += (float)wv[u] * (float)gv[u];
            }
            s += __shfl_xor(s, 1, 64);
            s += __shfl_xor(s, 2, 64);
            s += __shfl_xor(s, 4, 64);
            if (sub == 0) {
                float* dst = isk ? invk : invq;
                dst[cl & 127] = 1.0f / fmaxf(sqrtf(fmaxf(s, 0.0f)), 1e-12f);
            }
        }
    }
    __syncthreads();

    // ---- phase 2: logits (fragment-direct, no LDS staging) ----
    f32x4 acc[2][8] = {};
    const bf16* Aq = Wtq + (size_t)(qoff + wave * 32 + lm) * Cdim + quad * 8;
    const bf16* Bk = GWT + ((size_t)b * QKcols + koff + lm) * Cdim + quad * 8;
    for (int r0 = 0; r0 < Cdim; r0 += 32) {
        bf16x8 aq[2], bk[8];
#pragma unroll
        for (int mt = 0; mt < 2; mt++)
            aq[mt] = *reinterpret_cast<const bf16x8*>(Aq + (size_t)mt * 16 * Cdim + r0);
#pragma unroll
        for (int dt = 0; dt < 8; dt++)
            bk[dt] = *reinterpret_cast<const bf16x8*>(Bk + (size_t)dt * 16 * Cdim + r0);
#pragma unroll
        for (int mt = 0; mt < 2; mt++)
#pragma unroll
            for (int dt = 0; dt < 8; dt++)
                acc[mt][dt] = __builtin_amdgcn_mfma_f32_16x16x32_bf16(aq[mt], bk[dt], acc[mt][dt], 0, 0, 0);
    }

    // ---- phase 3: scale + softmax over d -> At (bf16, transposed) ----
    float ikv[8];
#pragma unroll
    for (int dt = 0; dt < 8; dt++) ikv[dt] = invk[dt * 16 + lm] * th;
#pragma unroll
    for (int mt = 0; mt < 2; mt++) {
#pragma unroll
        for (int r = 0; r < 4; r++) {
            const int c = wave * 32 + mt * 16 + quad * 4 + r;
            const float iq = invq[c];
            float v[8], m = -1e30f;
#pragma unroll
            for (int dt = 0; dt < 8; dt++) { v[dt] = acc[mt][dt][r] * iq * ikv[dt]; m = fmaxf(m, v[dt]); }
            m = fmaxf(m, __shfl_xor(m, 1, 64));
            m = fmaxf(m, __shfl_xor(m, 2, 64));
            m = fmaxf(m, __shfl_xor(m, 4, 64));
            m = fmaxf(m, __shfl_xor(m, 8, 64));
            float sum = 0.0f;
#pragma unroll
            for (int dt = 0; dt < 8; dt++) { v[dt] = __expf(v[dt] - m); sum += v[dt]; }
            sum += __shfl_xor(sum, 1, 64);
            sum += __shfl_xor(sum, 2, 64);
            sum += __shfl_xor(sum, 4, 64);
            sum += __shfl_xor(sum, 8, 64);
            const float inv = 1.0f / sum;
#pragma unroll
            for (int dt = 0; dt < 8; dt++)
                At[(dt * 16 + lm) * LDP + c] = __float2bfloat16(v[dt] * inv);
        }
    }
    __syncthreads();

    // ---- phase 4: Weff fold ----
    bf16* Wo = WeffT + (size_t)b * Cdim * Cdim + h * HD;
    for (int jo = 0; jo < Cdim; jo += 256) {
        const int jb = jo + wave * 64;
        f32x4 a2[4][8] = {};
#pragma unroll
        for (int ks = 0; ks < 4; ks++) {
            bf16x8 aw[4], bp[8];
#pragma unroll
            for (int mt = 0; mt < 4; mt++)
                aw[mt] = *reinterpret_cast<const bf16x8*>(Wtp + (size_t)(jb + mt * 16 + lm) * Cdim + h * HD + ks * 32 + quad * 8);
#pragma unroll
            for (int dt = 0; dt < 8; dt++)
                bp[dt] = *reinterpret_cast<const bf16x8*>(&At[(dt * 16 + lm) * LDP + ks * 32 + quad * 8]);
#pragma unroll
            for (int mt = 0; mt < 4; mt++)
#pragma unroll
                for (int dt = 0; dt < 8; dt++)
                    a2[mt][dt] = __builtin_amdgcn_mfma_f32_16x16x32_bf16(aw[mt], bp[dt], a2[mt][dt], 0, 0, 0);
        }
#pragma unroll
        for (int mt = 0; mt < 4; mt++)
#pragma unroll
            for (int dt = 0; dt < 8; dt++)
#pragma unroll
                for (int r = 0; r < 4; r++)
                    Wo[(size_t)(jb + mt * 16 + quad * 4 + r) * Cdim + dt * 16 + lm] =
                        __float2bfloat16(a2[mt][dt][r]);
    }
}

// ---------------------------------------------------------------------------
// Final GEMM with fused fp32->bf16 A staging and XCD-chunked swizzle.
// out[z*4096+m][n] = sum_k bf16(y[z][m][k]) * WeffT[z][n][k] + bias[n]
// 1536 blocks = 8 XCDs x 192 (XCD == batch under round-robin dispatch).
// ---------------------------------------------------------------------------
__global__ __launch_bounds__(256) void gemm_yfused(const float* __restrict__ Y,
                                                   const bf16* __restrict__ WeffT,
                                                   const float* __restrict__ bias,
                                                   float* __restrict__ out) {
    __shared__ bf16 As[128 * 32];
    __shared__ bf16 Bs[128 * 32];

    const int bid = blockIdx.x;
    const int z = bid & 7, rem = bid >> 3;        // z == XCD
    const int bx = rem % 6, by = rem / 6;
    const int m0 = by * 128, n0 = bx * 128;

    const int tid  = threadIdx.x;
    const int wave = tid >> 6, lane = tid & 63;
    const int wq   = wave >> 1, wr = wave & 1;
    const int lm   = lane & 15, quad = lane >> 4;

    const int srow = tid >> 2, scol = (tid & 3) * 8;
    const float* Ag = Y + (size_t)z * Ntok * Cdim + (size_t)(m0 + srow) * Cdim + scol;
    const bf16*  Bg = WeffT + (size_t)z * Cdim * Cdim + (size_t)(n0 + srow) * Cdim + scol;
    bf16* Al0 = &As[srow * 32 + scol];
    bf16* Al1 = &As[(64 + srow) * 32 + scol];
    bf16* Bl0 = &Bs[srow * 32 + scol];
    bf16* Bl1 = &Bs[(64 + srow) * 32 + scol];

    f32x4 acc[4][4] = {};

    for (int k0 = 0; k0 < Cdim; k0 += 32) {
        __syncthreads();
        gload_lds16(Bg + k0,                     Bl0);
        gload_lds16(Bg + (size_t)64 * Cdim + k0, Bl1);
        const int4 a0 = cvt8_f32_to_bf16(Ag + k0);
        const int4 a1 = cvt8_f32_to_bf16(Ag + (size_t)64 * Cdim + k0);
        *reinterpret_cast<int4*>(Al0) = a0;
        *reinterpret_cast<int4*>(Al1) = a1;
        __syncthreads();

        bf16x8 af[4], bfr[4];
#pragma unroll
        for (int t = 0; t < 4; t++) {
            af[t]  = *reinterpret_cast<const bf16x8*>(&As[(wq * 64 + t * 16 + lm) * 32 + quad * 8]);
            bfr[t] = *reinterpret_cast<const bf16x8*>(&Bs[(wr * 64 + t * 16 + lm) * 32 + quad * 8]);
        }
#pragma unroll
        for (int mt = 0; mt < 4; mt++)
#pragma unroll
            for (int nt = 0; nt < 4; nt++)
                acc[mt][nt] = __builtin_amdgcn_mfma_f32_16x16x32_bf16(af[mt], bfr[nt], acc[mt][nt], 0, 0, 0);
    }

    float* Ob = out + (size_t)z * Ntok * Cdim;
    const int cm = m0 + wq * 64, cn = n0 + wr * 64;
#pragma unroll
    for (int mt = 0; mt < 4; mt++)
#pragma unroll
        for (int nt = 0; nt < 4; nt++) {
            const int col = cn + nt * 16 + lm;
            const float bv = bias[col];
#pragma unroll
            for (int r = 0; r < 4; r++)
                Ob[(size_t)(cm + mt * 16 + quad * 4 + r) * Cdim + col] = acc[mt][nt][r] + bv;
        }
}

// ---------------------------------------------------------------------------
extern "C" void kernel_launch(void* const* d_in, const int* in_sizes, int n_in,
                              void* d_out, int out_size, void* d_ws, size_t ws_size,
                              hipStream_t stream) {
    const float* x     = (const float*)d_in[0];
    const float* y     = (const float*)d_in[1];
    const float* Wqkv  = (const float*)d_in[2];
    const float* temp  = (const float*)d_in[3];
    const float* Wproj = (const float*)d_in[4];
    const float* bproj = (const float*)d_in[5];
    float* out = (float*)d_out;

    char* ws = (char*)d_ws;
    size_t o = 0;
    bf16*  xT      = (bf16*)(ws + o); o += (size_t)8 * Cdim * Ntok * 2;            // 50.3 MB
    float* partial = (float*)(ws + o); o += (size_t)NTRI * 8 * SPLITK * 16384 * 4; // 44.0 MB
    bf16*  G       = (bf16*)(ws + o); o += (size_t)8 * Cdim * Cdim * 2;            //  9.4 MB
    bf16*  GWT     = (bf16*)(ws + o); o += (size_t)8 * QKcols * Cdim * 2;          // 18.9 MB
    bf16*  WeffT   = (bf16*)(ws + o); o += (size_t)8 * Cdim * Cdim * 2;            //  9.4 MB
    bf16*  Wt_qkv  = (bf16*)(ws + o); o += (size_t)QKcols * Cdim * 2;
    bf16*  Wt_proj = (bf16*)(ws + o); o += (size_t)Cdim * Cdim * 2;

    // 1. all fp32->bf16 transposes (x, Wqkv, Wproj)
    transpose_all<<<13152, 256, 0, stream>>>(x, xT, Wqkv, Wt_qkv, Wproj, Wt_proj);

    // 2. Gram split-K: partial = x_b^T x_b slices (XCD-chunked by batch)
    gram_k<<<NTRI * 8 * SPLITK, 256, 0, stream>>>(xT, partial);

    // 3. reduce partials -> G (bf16, symmetric)
    gram_reduce<<<dim3(NTRI, 8), 256, 0, stream>>>(partial, G);

    // 4. GWT[b][j][r] = (G_b @ W_qkv)^T = W_qkv^T G_b  (G symmetric)
    gemm_bt<<<dim3(Cdim / 128, QKcols / 128, 8), 256, 0, stream>>>(
        Wt_qkv, G, GWT, Cdim, Cdim,
        0, (size_t)Cdim * Cdim, (size_t)QKcols * Cdim);

    // 5. diag norms + logits + softmax + Weff fold (one block per (b,h))
    head_all<<<48, 256, 0, stream>>>(GWT, Wt_qkv, Wt_proj, temp, WeffT);

    // 6. out = y_b @ Weff_b + b_proj (fused fp32->bf16 A, XCD swizzle)
    gemm_yfused<<<1536, 256, 0, stream>>>(y, WeffT, bproj, out);
}